// Round 4
// baseline (1397.438 us; speedup 1.0000x reference)
//
#include <hip/hip_runtime.h>
#include <math.h>

typedef unsigned short ushort_t;
typedef unsigned int uint_t;
typedef __attribute__((ext_vector_type(8))) short bf16x8;
typedef __attribute__((ext_vector_type(4))) float f32x4;

#define NTOK 131072          // B*S
#define TM 16                // tokens per block
#define SROW 548             // A row stride in bf16 (274 dw == 18 mod 32 -> 4-way max on frag reads)
#define SROW2 274            // dword stride
#define K0P 160              // layer0 K padded (132 -> 160)
#define KHP 544              // hidden layers K padded (514 -> 544)
#define EPS 1e-5f

__device__ __forceinline__ ushort_t f2bf(float f) {
    uint_t x = __float_as_uint(f);
    x += 0x7FFFu + ((x >> 16) & 1u);   // RNE
    return (ushort_t)(x >> 16);
}
__device__ __forceinline__ float bf2f(ushort_t u) {
    return __uint_as_float(((uint_t)u) << 16);
}

#if defined(__has_builtin)
#  if __has_builtin(__builtin_amdgcn_cvt_pk_bf16_f32)
#    define HAVE_PK_BF16 1
#  endif
#endif

__device__ __forceinline__ uint_t pk_bf16(float a, float b) {
#ifdef HAVE_PK_BF16
    auto r = __builtin_amdgcn_cvt_pk_bf16_f32(a, b);
    union { decltype(r) v; uint_t u; } cv; cv.v = r;
    return cv.u;
#else
    return (uint_t)f2bf(a) | ((uint_t)f2bf(b) << 16);
#endif
}

// ---- weight prep: W[K][512] fp32 -> Wt[n][k] bf16 (zero-pad to Kpad), LDS transpose ----
__global__ __launch_bounds__(256) void prep_w(const float* __restrict__ W,
                                              ushort_t* __restrict__ dst,
                                              int K, int Kpad) {
    __shared__ float tile[32][33];
    const int k0 = blockIdx.x * 32;
    const int n0 = blockIdx.y * 32;
    const int tx = threadIdx.x & 31;   // n within tile
    const int ty = threadIdx.x >> 5;   // k phase (8 rows/pass)
    for (int kk = ty; kk < 32; kk += 8) {
        int k = k0 + kk;
        tile[kk][tx] = (k < K) ? W[k * 512 + n0 + tx] : 0.0f;
    }
    __syncthreads();
    const int nn = threadIdx.x >> 3;   // 0..31
    const int c  = threadIdx.x & 7;
    uint_t* d32 = (uint_t*)(dst + (n0 + nn) * Kpad + k0);
#pragma unroll
    for (int h = 0; h < 2; h++) {
        int kp = c + 8 * h;
        d32[kp] = pk_bf16(tile[2 * kp][nn], tile[2 * kp + 1][nn]);
    }
}

// One fused layer: 48x512 GEMM (primal + 2 tangents share B), bias, LN+softplus
// primal + LN/softplus JVP on tangents, bf16 write-back to A.
template<int KPAD>
__device__ __forceinline__ void do_layer(
    const ushort_t* __restrict__ Wt, const float* __restrict__ bb,
    const float* __restrict__ gg, const float* __restrict__ bev,
    ushort_t* A_s, float (*stat)[8])
{
    const int tid  = threadIdx.x;
    const int lane = tid & 63;
    const int w    = tid >> 6;      // wave 0..7
    const int q    = lane >> 4;     // quad 0..3
    const int c16  = lane & 15;
    const int nb   = w * 64;        // wave's 64-column base

    f32x4 acc[3][4];
#pragma unroll
    for (int m = 0; m < 3; m++)
#pragma unroll
        for (int j = 0; j < 4; j++) acc[m][j] = (f32x4){0.f, 0.f, 0.f, 0.f};

    const ushort_t* ap = A_s + c16 * SROW + q * 8;
    const ushort_t* bp = Wt + (nb + c16) * KPAD + q * 8;

#pragma unroll
    for (int ks = 0; ks < KPAD / 32; ks++) {
        bf16x8 af[3], bf[4];
#pragma unroll
        for (int m = 0; m < 3; m++)
            af[m] = *(const bf16x8*)(ap + m * (16 * SROW) + ks * 32);
#pragma unroll
        for (int j = 0; j < 4; j++)
            bf[j] = *(const bf16x8*)(bp + j * (16 * KPAD) + ks * 32);
#pragma unroll
        for (int m = 0; m < 3; m++)
#pragma unroll
            for (int j = 0; j < 4; j++)
                acc[m][j] = __builtin_amdgcn_mfma_f32_16x16x32_bf16(af[m], bf[j], acc[m][j], 0, 0, 0);
    }

    // bias on primal rows
#pragma unroll
    for (int j = 0; j < 4; j++) {
        float bv = bb[nb + 16 * j + c16];
#pragma unroll
        for (int r = 0; r < 4; r++) acc[0][j][r] += bv;
    }

    // wave-local LN stats (6 sums per token over this wave's 64 cols)
    float st[4][6];
#pragma unroll
    for (int r = 0; r < 4; r++) {
        float s1 = 0.f, s2 = 0.f, a0 = 0.f, x0 = 0.f, a1 = 0.f, x1 = 0.f;
#pragma unroll
        for (int j = 0; j < 4; j++) {
            float p = acc[0][j][r], u0 = acc[1][j][r], u1 = acc[2][j][r];
            s1 += p; s2 += p * p;
            a0 += u0; x0 += p * u0;
            a1 += u1; x1 += p * u1;
        }
        st[r][0] = s1; st[r][1] = s2; st[r][2] = a0; st[r][3] = x0; st[r][4] = a1; st[r][5] = x1;
    }
#pragma unroll
    for (int d = 1; d <= 8; d <<= 1)
#pragma unroll
        for (int r = 0; r < 4; r++)
#pragma unroll
            for (int s = 0; s < 6; s++) st[r][s] += __shfl_xor(st[r][s], d);
    if (c16 == 0) {
#pragma unroll
        for (int r = 0; r < 4; r++)
#pragma unroll
            for (int s = 0; s < 6; s++)
                atomicAdd(&stat[4 * q + r][s], st[r][s]);
    }
    __syncthreads();   // all K-loop reads of A done; stats complete

    // epilogue: per-lane LN params from raw sums, softplus(LN)+JVP, bf16 write-back
    float gv[4], bvv[4];
#pragma unroll
    for (int j = 0; j < 4; j++) {
        gv[j]  = gg[nb + 16 * j + c16];
        bvv[j] = bev[nb + 16 * j + c16];
    }
    const float inv = 1.0f / 512.0f;
#pragma unroll
    for (int r = 0; r < 4; r++) {
        const int tok = 4 * q + r;
        const f32x4 sA = *(const f32x4*)&stat[tok][0];
        const f32x4 sB = *(const f32x4*)&stat[tok][4];
        float mu  = sA[0] * inv;
        float var = sA[1] * inv - mu * mu;
        float rs  = rsqrtf(var + EPS);
        float dm0 = sA[2] * inv;
        float c0  = rs * (sA[3] * inv - mu * dm0);
        float dm1 = sB[0] * inv;
        float c1  = rs * (sB[1] * inv - mu * dm1);
        ushort_t* xr  = A_s + tok * SROW + 2;
        ushort_t* u0r = xr + 16 * SROW;
        ushort_t* u1r = xr + 32 * SROW;
#pragma unroll
        for (int jp = 0; jp < 2; jp++) {
            float sp2[2], dd0[2], dd1[2];
#pragma unroll
            for (int h = 0; h < 2; h++) {
                int j = jp * 2 + h;
                float p = acc[0][j][r], u0 = acc[1][j][r], u1 = acc[2][j][r];
                float xh = (p - mu) * rs;
                float y  = fmaf(xh, gv[j], bvv[j]);
                float e  = __expf(-fabsf(y));
                float rinv = 1.0f / (1.0f + e);
                float sig  = (y >= 0.f) ? rinv : e * rinv;
                sp2[h] = fmaxf(y, 0.f) + __logf(1.0f + e);
                float w0 = sig * gv[j] * rs;
                dd0[h] = w0 * (u0 - fmaf(xh, c0, dm0));
                dd1[h] = w0 * (u1 - fmaf(xh, c1, dm1));
            }
            int n0 = nb + 32 * jp + c16;
            int n1 = n0 + 16;
            uint_t ps = pk_bf16(sp2[0], sp2[1]);
            uint_t p0 = pk_bf16(dd0[0], dd0[1]);
            uint_t p1 = pk_bf16(dd1[0], dd1[1]);
            xr[n0]  = (ushort_t)ps;  xr[n1]  = (ushort_t)(ps >> 16);
            u0r[n0] = (ushort_t)p0;  u0r[n1] = (ushort_t)(p0 >> 16);
            u1r[n0] = (ushort_t)p1;  u1r[n1] = (ushort_t)(p1 >> 16);
        }
    }
    __syncthreads();   // A fully rewritten before next layer's K-loop
}

__global__ __launch_bounds__(512, 4) void ode_mfma(
    const float* __restrict__ t, const float* __restrict__ z, const float* __restrict__ cond,
    const ushort_t* __restrict__ Wt0, const ushort_t* __restrict__ Wt1, const ushort_t* __restrict__ Wt2,
    const float* __restrict__ b0, const float* __restrict__ g0, const float* __restrict__ be0,
    const float* __restrict__ b1, const float* __restrict__ g1, const float* __restrict__ be1,
    const float* __restrict__ b2, const float* __restrict__ g2, const float* __restrict__ be2,
    const float* __restrict__ W3, const float* __restrict__ b3,
    float* __restrict__ out)
{
    __shared__ ushort_t A_s[48 * SROW];            // rows 0..15 primal, 16..31 u0, 32..47 u1
    __shared__ __align__(16) float stat[3][16][8]; // per-layer LN raw sums (atomically accumulated)

    const int tid = threadIdx.x;
    uint_t* A32 = (uint_t*)A_s;

    // ---- selective zero-init ----
    {
        float* sp = &stat[0][0][0];
        for (int i = tid; i < 3 * 16 * 8; i += 512) sp[i] = 0.f;
    }
    for (int i = tid; i < 32 * 80; i += 512) {       // tangent rows, k<160
        int row = 16 + i / 80, d = i % 80;
        A32[row * SROW2 + d] = 0u;
    }
    for (int i = tid; i < 48 * 16; i += 512) {       // k 512..543, all rows
        int row = i >> 4, d = 256 + (i & 15);
        A32[row * SROW2 + d] = 0u;
    }
    for (int i = tid; i < 16 * 14; i += 512) {       // primal pad k 132..159
        int row = i / 14, d = 66 + (i % 14);
        A32[row * SROW2 + d] = 0u;
    }
    __syncthreads();

    const float te = t[0];
    const int bi = (blockIdx.x * TM) >> 6;           // 16 tokens share one batch row
    if (tid < TM) {
        int tok = tid;
        int gm  = blockIdx.x * TM + tok;
        float pos = (float)((gm & 63) + 1) * (1.0f / 64.0f);
        A32[tok * SROW2 + 0] = pk_bf16(te, pos);
        A32[tok * SROW2 + 1] = pk_bf16(z[gm * 2 + 0], z[gm * 2 + 1]);
        A_s[(16 + tok) * SROW + 2] = (ushort_t)0x3F80;   // u0 = e0
        A_s[(32 + tok) * SROW + 3] = (ushort_t)0x3F80;   // u1 = e1
    }
    for (int i = tid; i < TM * 64; i += 512) {
        int tok = i >> 6, c2 = i & 63;
        const float2 cv = *(const float2*)&cond[bi * 128 + 2 * c2];
        A32[tok * SROW2 + 2 + c2] = pk_bf16(cv.x, cv.y);
    }
    __syncthreads();

    do_layer<K0P>(Wt0, b0, g0, be0, A_s, stat[0]);
    do_layer<KHP>(Wt1, b1, g1, be1, A_s, stat[1]);
    do_layer<KHP>(Wt2, b2, g2, be2, A_s, stat[2]);

    // ---- layer 3: Kin=514 -> 2 outputs + divergence ----
    {
        int tok = tid >> 5;       // 0..15
        int l32 = tid & 31;
        int gm  = blockIdx.x * TM + tok;
        const float2* W3v = (const float2*)W3;
        float a0 = 0.f, a1 = 0.f, d0 = 0.f, d1 = 0.f;
        for (int k = l32; k < 514; k += 32) {
            float2 wv = W3v[k];
            float ax  = bf2f(A_s[tok * SROW + k]);
            float au0 = bf2f(A_s[(16 + tok) * SROW + k]);
            float au1 = bf2f(A_s[(32 + tok) * SROW + k]);
            a0 = fmaf(ax, wv.x, a0);
            a1 = fmaf(ax, wv.y, a1);
            d0 = fmaf(au0, wv.x, d0);
            d1 = fmaf(au1, wv.y, d1);
        }
#pragma unroll
        for (int d = 1; d <= 16; d <<= 1) {
            a0 += __shfl_xor(a0, d); a1 += __shfl_xor(a1, d);
            d0 += __shfl_xor(d0, d); d1 += __shfl_xor(d1, d);
        }
        if (l32 == 0) {
            out[gm * 2 + 0]    = a0 + b3[0];
            out[gm * 2 + 1]    = a1 + b3[1];
            out[NTOK * 2 + gm] = -(d0 + d1);
        }
    }
}

extern "C" void kernel_launch(void* const* d_in, const int* in_sizes, int n_in,
                              void* d_out, int out_size, void* d_ws, size_t ws_size,
                              hipStream_t stream) {
    const float* t    = (const float*)d_in[0];
    const float* z    = (const float*)d_in[1];
    const float* cond = (const float*)d_in[2];
    const float* W0   = (const float*)d_in[3];
    const float* b0   = (const float*)d_in[4];
    const float* g0   = (const float*)d_in[5];
    const float* be0  = (const float*)d_in[6];
    const float* W1   = (const float*)d_in[7];
    const float* b1   = (const float*)d_in[8];
    const float* g1   = (const float*)d_in[9];
    const float* be1  = (const float*)d_in[10];
    const float* W2   = (const float*)d_in[11];
    const float* b2   = (const float*)d_in[12];
    const float* g2   = (const float*)d_in[13];
    const float* be2  = (const float*)d_in[14];
    const float* W3   = (const float*)d_in[15];
    const float* b3   = (const float*)d_in[16];
    float* out = (float*)d_out;

    ushort_t* Wt0 = (ushort_t*)d_ws;                    // 512*160
    ushort_t* Wt1 = Wt0 + 512 * K0P;                    // 512*544
    ushort_t* Wt2 = Wt1 + 512 * KHP;                    // 512*544

    hipLaunchKernelGGL(prep_w, dim3(K0P / 32, 16), dim3(256), 0, stream, W0, Wt0, 132, K0P);
    hipLaunchKernelGGL(prep_w, dim3(KHP / 32, 16), dim3(256), 0, stream, W1, Wt1, 514, KHP);
    hipLaunchKernelGGL(prep_w, dim3(KHP / 32, 16), dim3(256), 0, stream, W2, Wt2, 514, KHP);

    hipLaunchKernelGGL(ode_mfma, dim3(NTOK / TM), dim3(512), 0, stream,
                       t, z, cond, Wt0, Wt1, Wt2,
                       b0, g0, be0, b1, g1, be1, b2, g2, be2, W3, b3, out);
}